// Round 1
// baseline (106.714 us; speedup 1.0000x reference)
//
#include <hip/hip_runtime.h>

// Per-channel symmetric quantization, channel_axis=0.
// weights: [4096, 16384] f32.  Outputs flat in d_out (all f32):
//   q  [4096*16384], scale [4096], zero_point [4096] (all zeros).
//
// One block per row. Row staged in registers (16 x float4 per thread at 256
// threads), absmax reduced via shfl_xor within each 64-lane wave + LDS across
// the 4 waves, then quantize from registers. Weights read from HBM exactly
// once; total traffic ~537 MB -> memory-bound, ~90 us floor at 6 TB/s.

#define ROWS 4096
#define COLS 16384
#define THREADS 256
#define F4_PER_ROW (COLS / 4)            // 4096 float4 per row
#define ITERS (F4_PER_ROW / THREADS)     // 16 float4 per thread

__global__ __launch_bounds__(THREADS)
void quant_perchannel_kernel(const float* __restrict__ w,
                             const int* __restrict__ bits_ptr,
                             float* __restrict__ q_out,
                             float* __restrict__ scale_out,
                             float* __restrict__ zp_out) {
    const int row = blockIdx.x;
    const int tid = threadIdx.x;

    const float4* wrow = reinterpret_cast<const float4*>(w) + (size_t)row * F4_PER_ROW;

    // Stage row in registers, tracking per-thread absmax.
    float4 v[ITERS];
    float m = 0.0f;
#pragma unroll
    for (int i = 0; i < ITERS; ++i) {
        v[i] = wrow[i * THREADS + tid];
        m = fmaxf(m, fmaxf(fmaxf(fabsf(v[i].x), fabsf(v[i].y)),
                           fmaxf(fabsf(v[i].z), fabsf(v[i].w))));
    }

    // Wave (64-lane) butterfly max reduction.
#pragma unroll
    for (int off = 1; off < 64; off <<= 1)
        m = fmaxf(m, __shfl_xor(m, off, 64));

    // Across the 4 waves via LDS.
    __shared__ float smax[THREADS / 64];
    const int wave = tid >> 6;
    if ((tid & 63) == 0) smax[wave] = m;
    __syncthreads();
    float bm = smax[0];
#pragma unroll
    for (int i = 1; i < THREADS / 64; ++i) bm = fmaxf(bm, smax[i]);

    const int bits = bits_ptr[0];
    const float qmax = (float)((1 << (bits - 1)) - 1);   // 127 for 8 bits
    const float scale = (bm > 0.0f) ? (bm / qmax) : 1.0f;
    const float inv = 1.0f / scale;

    // Quantize from registers and store (round-half-to-even like np/jnp.round).
    float4* qrow = reinterpret_cast<float4*>(q_out) + (size_t)row * F4_PER_ROW;
#pragma unroll
    for (int i = 0; i < ITERS; ++i) {
        float4 r;
        r.x = fminf(fmaxf(rintf(v[i].x * inv), -qmax), qmax);
        r.y = fminf(fmaxf(rintf(v[i].y * inv), -qmax), qmax);
        r.z = fminf(fmaxf(rintf(v[i].z * inv), -qmax), qmax);
        r.w = fminf(fmaxf(rintf(v[i].w * inv), -qmax), qmax);
        qrow[i * THREADS + tid] = r;
    }

    if (tid == 0) {
        scale_out[row] = scale;
        zp_out[row] = 0.0f;
    }
}

extern "C" void kernel_launch(void* const* d_in, const int* in_sizes, int n_in,
                              void* d_out, int out_size, void* d_ws, size_t ws_size,
                              hipStream_t stream) {
    const float* w = (const float*)d_in[0];
    const int* bits = (const int*)d_in[1];

    float* out = (float*)d_out;
    float* q_out = out;                                  // 4096*16384
    float* scale_out = out + (size_t)ROWS * COLS;        // 4096
    float* zp_out = scale_out + ROWS;                    // 4096

    quant_perchannel_kernel<<<ROWS, THREADS, 0, stream>>>(w, bits, q_out,
                                                          scale_out, zp_out);
}

// Round 3
// 93.227 us; speedup vs baseline: 1.1447x; 1.1447x over previous
//
#include <hip/hip_runtime.h>

// Per-channel symmetric quantization, channel_axis=0.
// weights: [4096, 16384] f32.  Outputs flat in d_out (all f32):
//   q [4096*16384], scale [4096], zero_point [4096] (zeros).
//
// One block per row, 512 threads, 8 x float4 per thread staged in registers
// (32 VGPRs) -> fits the 64-VGPR occupancy tier (32 waves/CU) for full
// latency hiding. Weights read from HBM exactly once. Nontemporal hints on
// both streams (touch-once data, no reuse). Native clang vector type because
// __builtin_nontemporal_* rejects HIP_vector_type structs.

#define ROWS 4096
#define COLS 16384
#define THREADS 512
#define F4_PER_ROW (COLS / 4)            // 4096 float4 per row
#define ITERS (F4_PER_ROW / THREADS)     // 8 float4 per thread
#define NWAVES (THREADS / 64)            // 8 waves

typedef float f32x4 __attribute__((ext_vector_type(4)));

__global__ __launch_bounds__(THREADS, 8)
void quant_perchannel_kernel(const float* __restrict__ w,
                             const int* __restrict__ bits_ptr,
                             float* __restrict__ q_out,
                             float* __restrict__ scale_out,
                             float* __restrict__ zp_out) {
    const int row = blockIdx.x;
    const int tid = threadIdx.x;

    const f32x4* wrow = reinterpret_cast<const f32x4*>(w) + (size_t)row * F4_PER_ROW;

    // Stage row in registers (nontemporal: streaming, no reuse), track absmax.
    f32x4 v[ITERS];
    float m = 0.0f;
#pragma unroll
    for (int i = 0; i < ITERS; ++i) {
        v[i] = __builtin_nontemporal_load(&wrow[i * THREADS + tid]);
        m = fmaxf(m, fmaxf(fmaxf(fabsf(v[i].x), fabsf(v[i].y)),
                           fmaxf(fabsf(v[i].z), fabsf(v[i].w))));
    }

    // Wave (64-lane) butterfly max reduction.
#pragma unroll
    for (int off = 1; off < 64; off <<= 1)
        m = fmaxf(m, __shfl_xor(m, off, 64));

    // Across waves via LDS.
    __shared__ float smax[NWAVES];
    const int wave = tid >> 6;
    if ((tid & 63) == 0) smax[wave] = m;
    __syncthreads();
    float bm = smax[0];
#pragma unroll
    for (int i = 1; i < NWAVES; ++i) bm = fmaxf(bm, smax[i]);

    const int bits = bits_ptr[0];
    const float qmax = (float)((1 << (bits - 1)) - 1);   // 127 for 8 bits
    const float scale = (bm > 0.0f) ? (bm / qmax) : 1.0f;
    const float inv = 1.0f / scale;

    // Quantize from registers, round-half-to-even, nontemporal store.
    f32x4* qrow = reinterpret_cast<f32x4*>(q_out) + (size_t)row * F4_PER_ROW;
#pragma unroll
    for (int i = 0; i < ITERS; ++i) {
        f32x4 r;
        r.x = fminf(fmaxf(rintf(v[i].x * inv), -qmax), qmax);
        r.y = fminf(fmaxf(rintf(v[i].y * inv), -qmax), qmax);
        r.z = fminf(fmaxf(rintf(v[i].z * inv), -qmax), qmax);
        r.w = fminf(fmaxf(rintf(v[i].w * inv), -qmax), qmax);
        __builtin_nontemporal_store(r, &qrow[i * THREADS + tid]);
    }

    if (tid == 0) {
        scale_out[row] = scale;
        zp_out[row] = 0.0f;
    }
}

extern "C" void kernel_launch(void* const* d_in, const int* in_sizes, int n_in,
                              void* d_out, int out_size, void* d_ws, size_t ws_size,
                              hipStream_t stream) {
    const float* w = (const float*)d_in[0];
    const int* bits = (const int*)d_in[1];

    float* out = (float*)d_out;
    float* q_out = out;                                  // 4096*16384
    float* scale_out = out + (size_t)ROWS * COLS;        // 4096
    float* zp_out = scale_out + ROWS;                    // 4096

    quant_perchannel_kernel<<<ROWS, THREADS, 0, stream>>>(w, bits, q_out,
                                                          scale_out, zp_out);
}